// Round 14
// baseline (1001.807 us; speedup 1.0000x reference)
//
#include <hip/hip_runtime.h>
#include <hip/hip_fp16.h>

// ManualRNN: B=32, T=2048, Fin=256, H=256, O=256 (all f32 in/out)
//   phase1: xh(f16) = x @ Wxh^T + bxh -> 2nd half of y region (dead before p3)
//   phase2: scan, r10 body verbatim (799us verified)
//   phase3: y(f32) = hs @ Why^T + by
//
// Ledger: scan step 933cy = ~620 MFMA-issue floor + ~310 lockstep serial tail;
// alternatives all measured worse (r5 flags, r8 VALU, r9/r12 fusion, r13
// preread - covers only 39cy of the 120cy window, multi-chunk preread
// impossible: other waves' data). Gap cost ~7us/dispatch (r13 split). GEMMs
// ~50us each vs 17 roofline, config-invariant w.r.t. work-per-dispatch ->
// latency/occupancy-bound. r14: GEMM occupancy 16->32 waves/CU (1 nt/wave,
// VGPR<=64 via launch_bounds(512,8), blockIdx.y col-half, 1024 blocks = 4/CU).

typedef _Float16 f16x8 __attribute__((ext_vector_type(8)));
typedef float    f32x4 __attribute__((ext_vector_type(4)));

#define MFMA16 __builtin_amdgcn_mfma_f32_16x16x32_f16

__device__ __forceinline__ f16x8 cvt8(const float* __restrict__ p) {
    float4 u = *(const float4*)p;
    float4 v = *(const float4*)(p + 4);
    f16x8 r;
    r[0] = (_Float16)u.x; r[1] = (_Float16)u.y; r[2] = (_Float16)u.z; r[3] = (_Float16)u.w;
    r[4] = (_Float16)v.x; r[5] = (_Float16)v.y; r[6] = (_Float16)v.z; r[7] = (_Float16)v.w;
    return r;
}

// C[m][n] = sum_k A[m][k]*W[n][k] + bias[n];  N=K=256.
// Grid (512, 2): blockIdx.x = M-tile of 128 rows, blockIdx.y = col half.
// 512 thr / 8 waves; wave w owns 16 cols (1 n-tile) -> B-frags 32 VGPR,
// total <=64 VGPR -> 32 waves/CU (4 blocks/CU, exactly resident at 1024 blocks).
template<bool AF16, bool OF16>
__global__ __launch_bounds__(512, 8) void gemm_nt_occ(
    const void* __restrict__ Av, const float* __restrict__ W,
    const float* __restrict__ bias, void* __restrict__ Cv) {
    const int tid = threadIdx.x;
    const int l  = tid & 63;
    const int w  = tid >> 6;        // 0..7
    const int lr = l & 15;
    const int lg = l >> 4;
    const long m0 = (long)blockIdx.x * 128;
    const int  n0 = blockIdx.y * 128 + w * 16;

    f16x8 wg[8];
    #pragma unroll
    for (int k = 0; k < 8; ++k)
        wg[k] = cvt8(W + (long)(n0 + lr) * 256 + k * 32 + lg * 8);

    const float bv = bias[n0 + lr];

    #pragma unroll 2
    for (int mt = 0; mt < 8; ++mt) {
        const long r0 = m0 + mt * 16 + lr;
        f32x4 ac = {0.f, 0.f, 0.f, 0.f};
        #pragma unroll
        for (int k = 0; k < 8; ++k) {
            const int kc = k * 32 + lg * 8;
            f16x8 a;
            if constexpr (AF16) a = *(const f16x8*)((const _Float16*)Av + r0 * 256 + kc);
            else                a = cvt8((const float*)Av + r0 * 256 + kc);
            ac = MFMA16(a, wg[k], ac, 0, 0, 0);
        }
        const int col = n0 + lr;
        #pragma unroll
        for (int d = 0; d < 4; ++d) {
            const long row = m0 + mt * 16 + lg * 4 + d;
            const float v = ac[d] + bv;
            if constexpr (OF16) ((_Float16*)Cv)[row * 256 + col] = (_Float16)v;
            else                ((float*)Cv)[row * 256 + col] = v;
        }
    }
}

// Recurrence: r10 body verbatim (799us verified). 32 blocks x 512 thr (8 waves).
__global__ __launch_bounds__(512, 1) void rnn_scan(
    const _Float16* __restrict__ xh, const float* __restrict__ h0,
    const float* __restrict__ Whh, _Float16* __restrict__ hs,
    float* __restrict__ hfin) {
    const int b   = blockIdx.x;
    const int tid = threadIdx.x;
    const int l   = tid & 63;
    const int w   = tid >> 6;   // 0..7
    const int lr  = l & 15;
    const int lg  = l >> 4;
    const int n0  = w * 32;

    __shared__ _Float16 hbuf[2][256];

    f16x8 wb[2][8];
    #pragma unroll
    for (int nt = 0; nt < 2; ++nt)
        #pragma unroll
        for (int k = 0; k < 8; ++k)
            wb[nt][k] = cvt8(Whh + (long)(n0 + nt * 16 + lr) * 256 + k * 32 + lg * 8);

    if (tid < 256) hbuf[0][tid] = (_Float16)h0[b * 256 + tid];
    __syncthreads();

    const int cl = n0 + (l & 31);
    const _Float16* xp = xh + (long)b * 2048 * 256 + cl;
    _Float16*       hp = hs + (long)b * 2048 * 256 + cl;

    float xcur[4], xnext[4];
    #pragma unroll
    for (int j = 0; j < 4; ++j) xcur[j] = (float)xp[(long)j * 256];

    for (int tb = 0; tb < 2048; tb += 4) {
        // next group's xh loads: ~2500cy cover >> 900cy HBM latency
        #pragma unroll
        for (int j = 0; j < 4; ++j) {
            long tn = tb + 4 + j; if (tn > 2047) tn = 2047;
            xnext[j] = (float)xp[tn * 256];
        }

        #pragma unroll
        for (int j = 0; j < 4; ++j) {
            const f16x8* hc = (const f16x8*)hbuf[j & 1];   // t&1 == j&1
            f16x8 af[8];
            #pragma unroll
            for (int k = 0; k < 8; ++k) af[k] = hc[k * 4 + lg];

            __builtin_amdgcn_s_setprio(1);
            const f32x4 zero = {0.f, 0.f, 0.f, 0.f};
            f32x4 accA[2], accB[2];              // split chains k0-3 / k4-7
            #pragma unroll
            for (int nt = 0; nt < 2; ++nt) {
                accA[nt] = MFMA16(af[0], wb[nt][0], zero, 0, 0, 0);
                accB[nt] = MFMA16(af[4], wb[nt][4], zero, 0, 0, 0);
            }
            #pragma unroll
            for (int k = 1; k < 4; ++k)
                #pragma unroll
                for (int nt = 0; nt < 2; ++nt) {
                    accA[nt] = MFMA16(af[k],     wb[nt][k],     accA[nt], 0, 0, 0);
                    accB[nt] = MFMA16(af[k + 4], wb[nt][k + 4], accB[nt], 0, 0, 0);
                }
            __builtin_amdgcn_s_setprio(0);

            // single tanh chain: select col's sum first
            const float s0 = accA[0][0] + accB[0][0];
            const float s1 = accA[1][0] + accB[1][0];
            const float s  = ((l & 16) ? s1 : s0) + xcur[j];
            const float e  = __expf(2.0f * s);
            const float v  = 1.0f - 2.0f * __builtin_amdgcn_rcpf(e + 1.0f);
            const _Float16 hv = (_Float16)v;

            if (l < 32) {
                hbuf[(j & 1) ^ 1][cl] = hv;              // next step's h
                hp[(long)(tb + j) * 256] = hv;           // fire-and-forget
            }

            // LDS-only barrier (no vmcnt drain)
            asm volatile("s_waitcnt lgkmcnt(0)" ::: "memory");
            __builtin_amdgcn_s_barrier();
            asm volatile("" ::: "memory");
        }

        #pragma unroll
        for (int j = 0; j < 4; ++j) xcur[j] = xnext[j];
    }

    // t=2047 wrote parity ((2047&1)^1)=0
    if (tid < 256) hfin[b * 256 + tid] = (float)hbuf[0][tid];
}

extern "C" void kernel_launch(void* const* d_in, const int* in_sizes, int n_in,
                              void* d_out, int out_size, void* d_ws, size_t ws_size,
                              hipStream_t stream) {
    const float* x   = (const float*)d_in[0];
    const float* h0  = (const float*)d_in[1];
    const float* Wxh = (const float*)d_in[2];
    const float* bxh = (const float*)d_in[3];
    const float* Whh = (const float*)d_in[4];
    const float* Why = (const float*)d_in[5];
    const float* by  = (const float*)d_in[6];

    float* y    = (float*)d_out;                   // (65536,256) f32
    float* hfin = y + (long)65536 * 256;           // (32,256) f32
    _Float16* xhf = (_Float16*)(y + (long)32768 * 256);  // xh f16, dead before phase3 writes
    _Float16* hs  = (_Float16*)d_ws;               // (65536,256) f16

    // phase1: xh(f16) = x @ Wxh^T + bxh   (4 blocks/CU occupancy experiment)
    gemm_nt_occ<false, true ><<<dim3(512, 2), 512, 0, stream>>>(x, Wxh, bxh, xhf);
    // phase2: scan
    rnn_scan<<<32, 512, 0, stream>>>(xhf, h0, Whh, hs, hfin);
    // phase3: y(f32) = hs @ Why^T + by
    gemm_nt_occ<true,  false><<<dim3(512, 2), 512, 0, stream>>>(hs, Why, by, y);
}